// Round 3
// baseline (12574.363 us; speedup 1.0000x reference)
//
#include <hip/hip_runtime.h>
#include <math.h>

#define TT 4096
#define HH 768
#define NHEAD 12
#define HDIM 64
#define NEXP 8
#define FDIM 1536
#define CAP 640
#define SEQ 2048
#define VOCAB 32000

// --------- input_ids normalize (robust to int32 or int64 host layout) ---------
__global__ __launch_bounds__(256) void k_ids(const int* __restrict__ in, int* __restrict__ outi) {
    __shared__ int is64;
    if (threadIdx.x == 0) {
        int o = 0;
        for (int i = 1; i < 128; i += 2) o |= in[i];
        is64 = (o == 0) ? 1 : 0;
    }
    __syncthreads();
    const int stride = is64 ? 2 : 1;
    for (int t = threadIdx.x + blockIdx.x * 256; t < TT; t += gridDim.x * 256) {
        int v = in[t * stride];
        v = v < 0 ? 0 : (v >= VOCAB ? VOCAB - 1 : v);
        outi[t] = v;
    }
}

__global__ __launch_bounds__(192) void k_embed(const int* __restrict__ ids, const float* __restrict__ ew,
                                               float* __restrict__ h) {
    const int t = blockIdx.x;
    const int id = ids[t];
    const float4* src = reinterpret_cast<const float4*>(ew + (size_t)id * HH);
    float4* dst = reinterpret_cast<float4*>(h + (size_t)t * HH);
    dst[threadIdx.x] = src[threadIdx.x];
}

__global__ __launch_bounds__(64) void k_ln(const float* __restrict__ x, const float* __restrict__ g,
                                           const float* __restrict__ b, float* __restrict__ y) {
    const int t = blockIdx.x;
    const int lane = threadIdx.x;
    const float* row = x + (size_t)t * HH;
    float v[12];
    float s = 0.f, sq = 0.f;
#pragma unroll
    for (int i = 0; i < 12; i++) {
        float f = row[lane + (i << 6)];
        v[i] = f; s += f; sq += f * f;
    }
#pragma unroll
    for (int off = 32; off; off >>= 1) { s += __shfl_xor(s, off); sq += __shfl_xor(sq, off); }
    const float mean = s * (1.f / 768.f);
    float var = sq * (1.f / 768.f) - mean * mean;
    var = fmaxf(var, 0.f);
    const float rstd = rsqrtf(var + 1e-5f);
    float* yr = y + (size_t)t * HH;
#pragma unroll
    for (int i = 0; i < 12; i++) {
        const int d = lane + (i << 6);
        yr[d] = (v[i] - mean) * rstd * g[d] + b[d];
    }
}

// ---------------- naive fp32 LDS-tiled SGEMM: C = A(MxK) * B (+bias/gelu/resid) ----------------
// BT: B is [N][K] (C = A*B^T), else B is [K][N]. All fp32. 64x64 tile, 256 thr, 4x4 per thread.
template<bool BT, bool XMAJ, bool BIAS, bool GELU, bool RESID>
__global__ __launch_bounds__(256) void k_sgemm(
    const float* __restrict__ A, const float* __restrict__ B,
    const float* __restrict__ bias, const float* __restrict__ resid,
    float* __restrict__ C,
    const int M, const int N, const int K,
    const long long eA, const long long eB, const long long eBias, const long long eC)
{
    const int e = blockIdx.z;
    A += e * eA; B += e * eB; C += e * eC;
    if (BIAS) bias += e * eBias;

    __shared__ float As[64][33];
    __shared__ float Bsk[32][65];   // [k][n]

    const int tid = threadIdx.x;
    const int ty = tid >> 4;        // 0..15
    const int tx = tid & 15;        // 0..15
    const int n0 = (XMAJ ? blockIdx.y : blockIdx.x) * 64;
    const int m0 = (XMAJ ? blockIdx.x : blockIdx.y) * 64;

    const int ar = tid >> 2;          // staged row 0..63
    const int ak = (tid & 3) << 3;    // 0,8,16,24

    float acc[4][4];
#pragma unroll
    for (int r = 0; r < 4; r++)
#pragma unroll
        for (int c = 0; c < 4; c++) acc[r][c] = 0.f;

    for (int k0 = 0; k0 < K; k0 += 32) {
        // stage A tile: As[row][k]
        {
            const float* ap = A + (size_t)(m0 + ar) * K + k0 + ak;
            const float4 x0 = *reinterpret_cast<const float4*>(ap);
            const float4 x1 = *reinterpret_cast<const float4*>(ap + 4);
            float* d = &As[ar][ak];
            d[0] = x0.x; d[1] = x0.y; d[2] = x0.z; d[3] = x0.w;
            d[4] = x1.x; d[5] = x1.y; d[6] = x1.z; d[7] = x1.w;
        }
        // stage B tile: Bsk[k][n]
        if constexpr (BT) {
            const float* bp = B + (size_t)(n0 + ar) * K + k0 + ak;
            const float4 x0 = *reinterpret_cast<const float4*>(bp);
            const float4 x1 = *reinterpret_cast<const float4*>(bp + 4);
            Bsk[ak + 0][ar] = x0.x; Bsk[ak + 1][ar] = x0.y;
            Bsk[ak + 2][ar] = x0.z; Bsk[ak + 3][ar] = x0.w;
            Bsk[ak + 4][ar] = x1.x; Bsk[ak + 5][ar] = x1.y;
            Bsk[ak + 6][ar] = x1.z; Bsk[ak + 7][ar] = x1.w;
        } else {
            const int kl = tid >> 3;          // 0..31
            const int ng = (tid & 7) << 3;    // 0,8,...,56
            const float* bp = B + (size_t)(k0 + kl) * N + n0 + ng;
            const float4 x0 = *reinterpret_cast<const float4*>(bp);
            const float4 x1 = *reinterpret_cast<const float4*>(bp + 4);
            float* d = &Bsk[kl][ng];
            d[0] = x0.x; d[1] = x0.y; d[2] = x0.z; d[3] = x0.w;
            d[4] = x1.x; d[5] = x1.y; d[6] = x1.z; d[7] = x1.w;
        }
        __syncthreads();
#pragma unroll 8
        for (int k = 0; k < 32; k++) {
            float a[4], b[4];
#pragma unroll
            for (int r = 0; r < 4; r++) a[r] = As[(ty << 2) + r][k];
#pragma unroll
            for (int c = 0; c < 4; c++) b[c] = Bsk[k][(tx << 2) + c];
#pragma unroll
            for (int r = 0; r < 4; r++)
#pragma unroll
                for (int c = 0; c < 4; c++) acc[r][c] += a[r] * b[c];
        }
        __syncthreads();
    }

#pragma unroll
    for (int c = 0; c < 4; c++) {
        const int col = n0 + (tx << 2) + c;
        float bv = 0.f;
        if constexpr (BIAS) bv = bias[col];
#pragma unroll
        for (int r = 0; r < 4; r++) {
            const int lrow = m0 + (ty << 2) + r;
            float v = acc[r][c] + bv;
            if constexpr (GELU) v = 0.5f * v * (1.f + erff(v * 0.70710678118654752f));
            if constexpr (RESID) v += resid[(size_t)lrow * N + col];
            C[(size_t)lrow * N + col] = v;
        }
    }
}

// ---------------- naive fp32 attention: one wave per query row ----------------
__global__ __launch_bounds__(64) void k_attn2(const float* __restrict__ q,
                                              const float* __restrict__ kf,
                                              const float* __restrict__ vf,
                                              const float* __restrict__ mask,
                                              float* __restrict__ out) {
    const int wid = blockIdx.x;          // 0 .. B*NH*SEQ-1
    const int qrow = wid & (SEQ - 1);
    const int bh = wid >> 11;            // 0..23
    const int nh = bh % NHEAD;
    const int b = bh / NHEAD;
    const int tq = b * SEQ + qrow;
    const int lane = threadIdx.x;

    __shared__ float qs[64];
    __shared__ float ps[SEQ];

    qs[lane] = q[(size_t)tq * HH + nh * HDIM + lane] * 0.125f;
    __syncthreads();

    const float* kb = kf + (size_t)b * SEQ * HDIM;
    const float* vb = vf + (size_t)b * SEQ * HDIM;
    const float* mb = mask + b * SEQ;

    float m = -3.4e38f;
    for (int j = lane; j < SEQ; j += 64) {
        float s = 0.f;
        const float* kr = kb + (size_t)j * HDIM;
#pragma unroll 16
        for (int d = 0; d < HDIM; d++) s += qs[d] * kr[d];
        s += (1.f - mb[j]) * -3.4028234663852886e38f;
        ps[j] = s;
        m = fmaxf(m, s);
    }
#pragma unroll
    for (int off = 32; off; off >>= 1) m = fmaxf(m, __shfl_xor(m, off));
    float lsum = 0.f;
    for (int j = lane; j < SEQ; j += 64) {
        const float p = __expf(ps[j] - m);
        ps[j] = p;
        lsum += p;
    }
#pragma unroll
    for (int off = 32; off; off >>= 1) lsum += __shfl_xor(lsum, off);
    const float inv = 1.f / lsum;
    __syncthreads();
    float o = 0.f;
    for (int j = 0; j < SEQ; j++) o += ps[j] * vb[(size_t)j * HDIM + lane];
    out[(size_t)tq * HH + nh * HDIM + lane] = o * inv;
}

// ---------------- gating: fp32 logits + softmax over 8 experts ----------------
__global__ __launch_bounds__(64) void k_gate(const float* __restrict__ x, const float* __restrict__ gw,
                                             float* __restrict__ scoresT) {
    const int t = blockIdx.x;
    const int lane = threadIdx.x;
    const float* row = x + (size_t)t * HH;
    float acc[8];
#pragma unroll
    for (int e = 0; e < 8; e++) acc[e] = 0.f;
    for (int d = lane; d < HH; d += 64) {
        const float xv = row[d];
#pragma unroll
        for (int e = 0; e < 8; e++) acc[e] += xv * gw[e * HH + d];
    }
#pragma unroll
    for (int e = 0; e < 8; e++) {
#pragma unroll
        for (int off = 32; off; off >>= 1) acc[e] += __shfl_xor(acc[e], off);
    }
    if (lane == 0) {
        float mx = acc[0];
#pragma unroll
        for (int e = 1; e < 8; e++) mx = fmaxf(mx, acc[e]);
        float ex[8], ssum = 0.f;
#pragma unroll
        for (int e = 0; e < 8; e++) { ex[e] = __expf(acc[e] - mx); ssum += ex[e]; }
        const float inv = 1.f / ssum;
#pragma unroll
        for (int e = 0; e < 8; e++) scoresT[(size_t)e * TT + t] = ex[e] * inv;
    }
}

// ---------------- per-expert exact top-640 via bitonic sort (jax tie-break) ----------------
__global__ __launch_bounds__(1024) void k_topk(const float* __restrict__ scoresT,
                                               int* __restrict__ top_i, float* __restrict__ top_s) {
    __shared__ unsigned long long keys[4096];
    const int e = blockIdx.x;
    const int tid = threadIdx.x;
    for (int i = tid; i < 4096; i += 1024) {
        const float sv = scoresT[(size_t)e * TT + i];
        keys[i] = (((unsigned long long)__float_as_uint(sv)) << 32) |
                  (unsigned long long)(0xFFFFFFFFu - (unsigned)i);
    }
    __syncthreads();
    for (int k = 2; k <= 4096; k <<= 1) {
        for (int j = k >> 1; j > 0; j >>= 1) {
            for (int i = tid; i < 4096; i += 1024) {
                const int ixj = i ^ j;
                if (ixj > i) {
                    const bool up = ((i & k) == 0);
                    const unsigned long long a = keys[i], bb = keys[ixj];
                    if ((a > bb) == up) { keys[i] = bb; keys[ixj] = a; }
                }
            }
            __syncthreads();
        }
    }
    for (int c = tid; c < CAP; c += 1024) {
        const unsigned long long u = keys[4095 - c];
        top_i[e * CAP + c] = (int)(0xFFFFFFFFu - (unsigned)(u & 0xFFFFFFFFull));
        top_s[e * CAP + c] = __uint_as_float((unsigned)(u >> 32));
    }
}

// ---------------- explicit gather / scatter for MoE (fp32) ----------------
__global__ __launch_bounds__(192) void k_gather(const int* __restrict__ top_i, const float* __restrict__ hn,
                                                float* __restrict__ xg) {
    const int ec = blockIdx.x;           // e*CAP + c
    const int tok = top_i[ec];
    const float4 v = *reinterpret_cast<const float4*>(hn + (size_t)tok * HH + threadIdx.x * 4);
    *reinterpret_cast<float4*>(xg + (size_t)ec * HH + threadIdx.x * 4) = v;
}

__global__ __launch_bounds__(192) void k_scatter(const int* __restrict__ top_i, const float* __restrict__ top_s,
                                                 const float* __restrict__ oute, float* __restrict__ h) {
    const int ec = blockIdx.x;
    const int tok = top_i[ec];
    const float sc = top_s[ec];
    const float4 v = *reinterpret_cast<const float4*>(oute + (size_t)ec * HH + threadIdx.x * 4);
    float* dst = h + (size_t)tok * HH + threadIdx.x * 4;
    atomicAdd(dst + 0, v.x * sc);
    atomicAdd(dst + 1, v.y * sc);
    atomicAdd(dst + 2, v.z * sc);
    atomicAdd(dst + 3, v.w * sc);
}

__global__ __launch_bounds__(512) void k_lb(const float* __restrict__ top_s, float* __restrict__ lb_out) {
    __shared__ float sums[8];
    const int w = threadIdx.x >> 6, lane = threadIdx.x & 63;
    float s = 0.f;
    for (int c = lane; c < CAP; c += 64) s += top_s[w * CAP + c];
#pragma unroll
    for (int off = 32; off; off >>= 1) s += __shfl_xor(s, off);
    if (lane == 0) sums[w] = s;
    __syncthreads();
    if (threadIdx.x == 0) {
        float mean = 0.f, load[8];
#pragma unroll
        for (int e2 = 0; e2 < 8; e2++) { load[e2] = sums[e2] * (1.f / 4096.f); mean += load[e2]; }
        mean *= 0.125f;
        float var = 0.f;
#pragma unroll
        for (int e2 = 0; e2 < 8; e2++) { const float d = load[e2] - mean; var += d * d; }
        lb_out[0] = var * (1.f / 7.f) * 8.f;
    }
}

__global__ void k_fin(const float* __restrict__ lb, float* __restrict__ dst) {
    if (threadIdx.x == 0 && blockIdx.x == 0) dst[0] = lb[0] + lb[1];
}

extern "C" void kernel_launch(void* const* d_in, const int* in_sizes, int n_in,
                              void* d_out, int out_size, void* d_ws, size_t ws_size,
                              hipStream_t stream)
{
    const int*   ids_raw = (const int*)d_in[0];
    const float* mask  = (const float*)d_in[1];
    const float* embw  = (const float*)d_in[2];
    const float* ln1g  = (const float*)d_in[3];
    const float* ln1b  = (const float*)d_in[4];
    const float* qw    = (const float*)d_in[5];
    const float* kw    = (const float*)d_in[6];
    const float* vw    = (const float*)d_in[7];
    const float* ow    = (const float*)d_in[8];
    const float* ln2g  = (const float*)d_in[9];
    const float* ln2b  = (const float*)d_in[10];
    const float* gw    = (const float*)d_in[11];
    const float* w1    = (const float*)d_in[12];
    const float* b1    = (const float*)d_in[13];
    const float* w2    = (const float*)d_in[14];
    const float* b2    = (const float*)d_in[15];
    const float* lnfg  = (const float*)d_in[16];
    const float* lnfb  = (const float*)d_in[17];
    const float* headw = (const float*)d_in[18];
    float* out = (float*)d_out;

    // ---- workspace layout (same footprint as round 2, proven fit) ----
    char* wsb = (char*)d_ws;
    size_t off = 0;
    auto alloc = [&](size_t bytes) -> void* {
        off = (off + 255) & ~(size_t)255;
        void* p = wsb + off;
        off += bytes;
        return p;
    };
    float* h0  = (float*)alloc((size_t)TT * HH * 4);
    float* h1b = (float*)alloc((size_t)TT * HH * 4);
    float* hn  = (float*)alloc((size_t)TT * HH * 4);
    float* q   = (float*)alloc((size_t)TT * HH * 4);
    float* kf  = (float*)alloc((size_t)TT * HDIM * 4);
    float* vf  = (float*)alloc((size_t)TT * HDIM * 4);
    float* scoresT = (float*)alloc((size_t)NEXP * TT * 4);
    int*   idsn    = (int*)alloc((size_t)TT * 4);
    int*   top_i   = (int*)alloc((size_t)NEXP * CAP * 4);
    float* top_s   = (float*)alloc((size_t)NEXP * CAP * 4);
    float* lb      = (float*)alloc(64);
    if (off > ws_size) return;

    // ---- transient MoE scratch in d_out (dead before head GEMM writes logits) ----
    char* outb = (char*)d_out;
    size_t ooff = 0;
    auto oalloc = [&](size_t bytes) -> void* {
        ooff = (ooff + 255) & ~(size_t)255;
        void* p = outb + ooff;
        ooff += bytes;
        return p;
    };
    float* xg   = (float*)oalloc((size_t)NEXP * CAP * HH * 4);    // gathered inputs
    float* act  = (float*)oalloc((size_t)NEXP * CAP * FDIM * 4);  // gelu(w1) activations
    float* oute = (float*)oalloc((size_t)NEXP * CAP * HH * 4);    // expert outputs

    k_ids<<<16, 256, 0, stream>>>(ids_raw, idsn);
    k_embed<<<TT, 192, 0, stream>>>(idsn, embw, h0);

    float* hc = h0;
    float* ho = h1b;
    for (int l = 0; l < 2; l++) {
        k_ln<<<TT, 64, 0, stream>>>(hc, ln1g + l * HH, ln1b + l * HH, hn);
        k_sgemm<true,false,false,false,false>
            <<<dim3(HH/64, TT/64, 1), 256, 0, stream>>>(
            hn, qw + (size_t)l * HH * HH, nullptr, nullptr, q, TT, HH, HH, 0, 0, 0, 0);
        k_sgemm<true,false,false,false,false>
            <<<dim3(1, TT/64, 1), 256, 0, stream>>>(
            hn, kw + (size_t)l * HDIM * HH, nullptr, nullptr, kf, TT, HDIM, HH, 0, 0, 0, 0);
        k_sgemm<true,false,false,false,false>
            <<<dim3(1, TT/64, 1), 256, 0, stream>>>(
            hn, vw + (size_t)l * HDIM * HH, nullptr, nullptr, vf, TT, HDIM, HH, 0, 0, 0, 0);
        k_attn2<<<2 * NHEAD * SEQ, 64, 0, stream>>>(q, kf, vf, mask, hn);
        k_sgemm<true,false,false,false,true>
            <<<dim3(HH/64, TT/64, 1), 256, 0, stream>>>(
            hn, ow + (size_t)l * HH * HH, nullptr, hc, ho, TT, HH, HH, 0, 0, 0, 0);
        k_ln<<<TT, 64, 0, stream>>>(ho, ln2g + l * HH, ln2b + l * HH, hn);
        k_gate<<<TT, 64, 0, stream>>>(hn, gw + (size_t)l * NEXP * HH, scoresT);
        k_topk<<<NEXP, 1024, 0, stream>>>(scoresT, top_i, top_s);
        k_gather<<<NEXP * CAP, 192, 0, stream>>>(top_i, hn, xg);
        k_sgemm<false,false,true,true,false>
            <<<dim3(FDIM/64, CAP/64, NEXP), 256, 0, stream>>>(
            xg, w1 + (size_t)l * NEXP * HH * FDIM, b1 + (size_t)l * NEXP * FDIM, nullptr, act,
            CAP, FDIM, HH, (long long)CAP * HH, (long long)HH * FDIM, FDIM, (long long)CAP * FDIM);
        k_sgemm<false,false,true,false,false>
            <<<dim3(HH/64, CAP/64, NEXP), 256, 0, stream>>>(
            act, w2 + (size_t)l * NEXP * FDIM * HH, b2 + (size_t)l * NEXP * HH, nullptr, oute,
            CAP, HH, FDIM, (long long)CAP * FDIM, (long long)FDIM * HH, HH, (long long)CAP * HH);
        k_scatter<<<NEXP * CAP, 192, 0, stream>>>(top_i, top_s, oute, ho);
        k_lb<<<1, 512, 0, stream>>>(top_s, lb + l);
        float* tmp = hc; hc = ho; ho = tmp;
    }
    k_ln<<<TT, 64, 0, stream>>>(hc, lnfg, lnfb, hn);
    k_sgemm<true,true,false,false,false>
        <<<dim3(TT/64, VOCAB/64, 1), 256, 0, stream>>>(
        hn, headw, nullptr, nullptr, out, TT, VOCAB, HH, 0, 0, 0, 0);
    k_fin<<<1, 64, 0, stream>>>(lb, out + (size_t)TT * VOCAB);
}

// Round 4
// 9439.690 us; speedup vs baseline: 1.3321x; 1.3321x over previous
//
#include <hip/hip_runtime.h>
#include <math.h>

#define TT 4096
#define HH 768
#define NHEAD 12
#define HDIM 64
#define NEXP 8
#define FDIM 1536
#define CAP 640
#define SEQ 2048
#define VOCAB 32000

typedef __attribute__((ext_vector_type(4))) float f32x4;
typedef __attribute__((ext_vector_type(8))) short bf16x8;

__device__ __forceinline__ unsigned short f2bf(float f) {
    unsigned int u = __float_as_uint(f);
    unsigned int r = u + 0x7fffu + ((u >> 16) & 1u);
    return (unsigned short)(r >> 16);
}

// --------- input_ids normalize (robust to int32 or int64 host layout) ---------
__global__ __launch_bounds__(256) void k_ids(const int* __restrict__ in, int* __restrict__ outi) {
    __shared__ int is64;
    if (threadIdx.x == 0) {
        int o = 0;
        for (int i = 1; i < 128; i += 2) o |= in[i];
        is64 = (o == 0) ? 1 : 0;
    }
    __syncthreads();
    const int stride = is64 ? 2 : 1;
    for (int t = threadIdx.x + blockIdx.x * 256; t < TT; t += gridDim.x * 256) {
        int v = in[t * stride];
        v = v < 0 ? 0 : (v >= VOCAB ? VOCAB - 1 : v);
        outi[t] = v;
    }
}

__global__ __launch_bounds__(192) void k_embed(const int* __restrict__ ids, const float* __restrict__ ew,
                                               float* __restrict__ h) {
    const int t = blockIdx.x;
    const int id = ids[t];
    const float4* src = reinterpret_cast<const float4*>(ew + (size_t)id * HH);
    float4* dst = reinterpret_cast<float4*>(h + (size_t)t * HH);
    dst[threadIdx.x] = src[threadIdx.x];
}

__global__ __launch_bounds__(64) void k_ln(const float* __restrict__ x, const float* __restrict__ g,
                                           const float* __restrict__ b, float* __restrict__ y) {
    const int t = blockIdx.x;
    const int lane = threadIdx.x;
    const float* row = x + (size_t)t * HH;
    float v[12];
    float s = 0.f, sq = 0.f;
#pragma unroll
    for (int i = 0; i < 12; i++) {
        float f = row[lane + (i << 6)];
        v[i] = f; s += f; sq += f * f;
    }
#pragma unroll
    for (int off = 32; off; off >>= 1) { s += __shfl_xor(s, off); sq += __shfl_xor(sq, off); }
    const float mean = s * (1.f / 768.f);
    float var = sq * (1.f / 768.f) - mean * mean;
    var = fmaxf(var, 0.f);
    const float rstd = rsqrtf(var + 1e-5f);
    float* yr = y + (size_t)t * HH;
#pragma unroll
    for (int i = 0; i < 12; i++) {
        const int d = lane + (i << 6);
        yr[d] = (v[i] - mean) * rstd * g[d] + b[d];
    }
}

// ---------------- bf16-MFMA GEMM (round-2 core, verbatim): C = A(MxK) * B ----------------
// BT: B is [N][K] (C = A*B^T), else B is [K][N].
template<bool BT, bool XMAJ, bool BIAS, bool GELU, bool RESID, typename AT, typename OT>
__global__ __launch_bounds__(256) void k_gemm(
    const AT* __restrict__ A, const float* __restrict__ B,
    const float* __restrict__ bias, const float* __restrict__ resid,
    OT* __restrict__ C,
    const int M, const int N, const int K,
    const long long eA, const long long eB, const long long eBias, const long long eC)
{
    const int e = blockIdx.z;
    A += e * eA; B += e * eB; C += e * eC;
    if (BIAS) bias += e * eBias;

    __shared__ __align__(16) short As[64][40];
    __shared__ __align__(16) short Bs[64][40];

    const int tid = threadIdx.x;
    const int lane = tid & 63;
    const int w = tid >> 6;
    const int n0 = (XMAJ ? blockIdx.y : blockIdx.x) * 64;
    const int m0 = (XMAJ ? blockIdx.x : blockIdx.y) * 64;

    f32x4 zero = {0.f, 0.f, 0.f, 0.f};
    f32x4 acc[4];
#pragma unroll
    for (int c = 0; c < 4; c++) acc[c] = zero;

    const int ar = tid >> 2;          // staged row 0..63
    const int ak = (tid & 3) << 3;    // 0,8,16,24
    const AT* aptr = A + (size_t)(m0 + ar) * K + ak;

    for (int k0 = 0; k0 < K; k0 += 32) {
        // stage A tile (convert to bf16 if fp32)
        if constexpr (sizeof(AT) == 4) {
            const float* ap = reinterpret_cast<const float*>(aptr) + k0;
            const float4 x0 = *reinterpret_cast<const float4*>(ap);
            const float4 x1 = *reinterpret_cast<const float4*>(ap + 4);
            short* d = &As[ar][ak];
            d[0] = (short)f2bf(x0.x); d[1] = (short)f2bf(x0.y);
            d[2] = (short)f2bf(x0.z); d[3] = (short)f2bf(x0.w);
            d[4] = (short)f2bf(x1.x); d[5] = (short)f2bf(x1.y);
            d[6] = (short)f2bf(x1.z); d[7] = (short)f2bf(x1.w);
        } else {
            const unsigned short* ap = reinterpret_cast<const unsigned short*>(aptr) + k0;
            *reinterpret_cast<int4*>(&As[ar][ak]) = *reinterpret_cast<const int4*>(ap);
        }
        // stage B tile as Bs[n][k]
        if constexpr (BT) {
            const float* bp = B + (size_t)(n0 + ar) * K + k0 + ak;
            const float4 x0 = *reinterpret_cast<const float4*>(bp);
            const float4 x1 = *reinterpret_cast<const float4*>(bp + 4);
            short* d = &Bs[ar][ak];
            d[0] = (short)f2bf(x0.x); d[1] = (short)f2bf(x0.y);
            d[2] = (short)f2bf(x0.z); d[3] = (short)f2bf(x0.w);
            d[4] = (short)f2bf(x1.x); d[5] = (short)f2bf(x1.y);
            d[6] = (short)f2bf(x1.z); d[7] = (short)f2bf(x1.w);
        } else {
            const int kk = tid >> 6;
            const int nn = tid & 63;
#pragma unroll
            for (int it = 0; it < 8; it++) {
                const int kl = kk + (it << 2);
                Bs[nn][kl] = (short)f2bf(B[(size_t)(k0 + kl) * N + n0 + nn]);
            }
        }
        __syncthreads();
        const bf16x8 af = *reinterpret_cast<const bf16x8*>(&As[(w << 4) + (lane & 15)][(lane >> 4) << 3]);
#pragma unroll
        for (int c = 0; c < 4; c++) {
            const bf16x8 bfr = *reinterpret_cast<const bf16x8*>(&Bs[(c << 4) + (lane & 15)][(lane >> 4) << 3]);
            acc[c] = __builtin_amdgcn_mfma_f32_16x16x32_bf16(af, bfr, acc[c], 0, 0, 0);
        }
        __syncthreads();
    }

    const int rb = (w << 4) + ((lane >> 4) << 2);
    const int cl = lane & 15;
#pragma unroll
    for (int c = 0; c < 4; c++) {
        const int col = n0 + (c << 4) + cl;
        float bv = 0.f;
        if constexpr (BIAS) bv = bias[col];
#pragma unroll
        for (int r = 0; r < 4; r++) {
            const int lrow = m0 + rb + r;
            float v = acc[c][r] + bv;
            if constexpr (GELU) v = 0.5f * v * (1.f + erff(v * 0.70710678118654752f));
            if constexpr (RESID) v += resid[(size_t)lrow * N + col];
            if constexpr (sizeof(OT) == 2) {
                C[(size_t)lrow * N + col] = (OT)f2bf(v);
            } else {
                C[(size_t)lrow * N + col] = v;
            }
        }
    }
}

// ---------------- naive fp32 LDS-tiled SGEMM (passing round-3 core) ----------------
template<bool BT, bool XMAJ, bool BIAS, bool GELU, bool RESID>
__global__ __launch_bounds__(256) void k_sgemm(
    const float* __restrict__ A, const float* __restrict__ B,
    const float* __restrict__ bias, const float* __restrict__ resid,
    float* __restrict__ C,
    const int M, const int N, const int K,
    const long long eA, const long long eB, const long long eBias, const long long eC)
{
    const int e = blockIdx.z;
    A += e * eA; B += e * eB; C += e * eC;
    if (BIAS) bias += e * eBias;

    __shared__ float As[64][33];
    __shared__ float Bsk[32][65];   // [k][n]

    const int tid = threadIdx.x;
    const int ty = tid >> 4;
    const int tx = tid & 15;
    const int n0 = (XMAJ ? blockIdx.y : blockIdx.x) * 64;
    const int m0 = (XMAJ ? blockIdx.x : blockIdx.y) * 64;

    const int ar = tid >> 2;
    const int ak = (tid & 3) << 3;

    float acc[4][4];
#pragma unroll
    for (int r = 0; r < 4; r++)
#pragma unroll
        for (int c = 0; c < 4; c++) acc[r][c] = 0.f;

    for (int k0 = 0; k0 < K; k0 += 32) {
        {
            const float* ap = A + (size_t)(m0 + ar) * K + k0 + ak;
            const float4 x0 = *reinterpret_cast<const float4*>(ap);
            const float4 x1 = *reinterpret_cast<const float4*>(ap + 4);
            float* d = &As[ar][ak];
            d[0] = x0.x; d[1] = x0.y; d[2] = x0.z; d[3] = x0.w;
            d[4] = x1.x; d[5] = x1.y; d[6] = x1.z; d[7] = x1.w;
        }
        if constexpr (BT) {
            const float* bp = B + (size_t)(n0 + ar) * K + k0 + ak;
            const float4 x0 = *reinterpret_cast<const float4*>(bp);
            const float4 x1 = *reinterpret_cast<const float4*>(bp + 4);
            Bsk[ak + 0][ar] = x0.x; Bsk[ak + 1][ar] = x0.y;
            Bsk[ak + 2][ar] = x0.z; Bsk[ak + 3][ar] = x0.w;
            Bsk[ak + 4][ar] = x1.x; Bsk[ak + 5][ar] = x1.y;
            Bsk[ak + 6][ar] = x1.z; Bsk[ak + 7][ar] = x1.w;
        } else {
            const int kl = tid >> 3;
            const int ng = (tid & 7) << 3;
            const float* bp = B + (size_t)(k0 + kl) * N + n0 + ng;
            const float4 x0 = *reinterpret_cast<const float4*>(bp);
            const float4 x1 = *reinterpret_cast<const float4*>(bp + 4);
            float* d = &Bsk[kl][ng];
            d[0] = x0.x; d[1] = x0.y; d[2] = x0.z; d[3] = x0.w;
            d[4] = x1.x; d[5] = x1.y; d[6] = x1.z; d[7] = x1.w;
        }
        __syncthreads();
#pragma unroll 8
        for (int k = 0; k < 32; k++) {
            float a[4], b[4];
#pragma unroll
            for (int r = 0; r < 4; r++) a[r] = As[(ty << 2) + r][k];
#pragma unroll
            for (int c = 0; c < 4; c++) b[c] = Bsk[k][(tx << 2) + c];
#pragma unroll
            for (int r = 0; r < 4; r++)
#pragma unroll
                for (int c = 0; c < 4; c++) acc[r][c] += a[r] * b[c];
        }
        __syncthreads();
    }

#pragma unroll
    for (int c = 0; c < 4; c++) {
        const int col = n0 + (tx << 2) + c;
        float bv = 0.f;
        if constexpr (BIAS) bv = bias[col];
#pragma unroll
        for (int r = 0; r < 4; r++) {
            const int lrow = m0 + (ty << 2) + r;
            float v = acc[r][c] + bv;
            if constexpr (GELU) v = 0.5f * v * (1.f + erff(v * 0.70710678118654752f));
            if constexpr (RESID) v += resid[(size_t)lrow * N + col];
            C[(size_t)lrow * N + col] = v;
        }
    }
}

// ---------------- naive fp32 attention: one wave per query row ----------------
__global__ __launch_bounds__(64) void k_attn2(const float* __restrict__ q,
                                              const float* __restrict__ kf,
                                              const float* __restrict__ vf,
                                              const float* __restrict__ mask,
                                              float* __restrict__ out) {
    const int wid = blockIdx.x;
    const int qrow = wid & (SEQ - 1);
    const int bh = wid >> 11;
    const int nh = bh % NHEAD;
    const int b = bh / NHEAD;
    const int tq = b * SEQ + qrow;
    const int lane = threadIdx.x;

    __shared__ float qs[64];
    __shared__ float ps[SEQ];

    qs[lane] = q[(size_t)tq * HH + nh * HDIM + lane] * 0.125f;
    __syncthreads();

    const float* kb = kf + (size_t)b * SEQ * HDIM;
    const float* vb = vf + (size_t)b * SEQ * HDIM;
    const float* mb = mask + b * SEQ;

    float m = -3.4e38f;
    for (int j = lane; j < SEQ; j += 64) {
        float s = 0.f;
        const float* kr = kb + (size_t)j * HDIM;
#pragma unroll 16
        for (int d = 0; d < HDIM; d++) s += qs[d] * kr[d];
        s += (1.f - mb[j]) * -3.4028234663852886e38f;
        ps[j] = s;
        m = fmaxf(m, s);
    }
#pragma unroll
    for (int off = 32; off; off >>= 1) m = fmaxf(m, __shfl_xor(m, off));
    float lsum = 0.f;
    for (int j = lane; j < SEQ; j += 64) {
        const float p = __expf(ps[j] - m);
        ps[j] = p;
        lsum += p;
    }
#pragma unroll
    for (int off = 32; off; off >>= 1) lsum += __shfl_xor(lsum, off);
    const float inv = 1.f / lsum;
    __syncthreads();
    float o = 0.f;
    for (int j = 0; j < SEQ; j++) o += ps[j] * vb[(size_t)j * HDIM + lane];
    out[(size_t)tq * HH + nh * HDIM + lane] = o * inv;
}

// ---------------- gating: fp32 logits + softmax over 8 experts ----------------
__global__ __launch_bounds__(64) void k_gate(const float* __restrict__ x, const float* __restrict__ gw,
                                             float* __restrict__ scoresT) {
    const int t = blockIdx.x;
    const int lane = threadIdx.x;
    const float* row = x + (size_t)t * HH;
    float acc[8];
#pragma unroll
    for (int e = 0; e < 8; e++) acc[e] = 0.f;
    for (int d = lane; d < HH; d += 64) {
        const float xv = row[d];
#pragma unroll
        for (int e = 0; e < 8; e++) acc[e] += xv * gw[e * HH + d];
    }
#pragma unroll
    for (int e = 0; e < 8; e++) {
#pragma unroll
        for (int off = 32; off; off >>= 1) acc[e] += __shfl_xor(acc[e], off);
    }
    if (lane == 0) {
        float mx = acc[0];
#pragma unroll
        for (int e = 1; e < 8; e++) mx = fmaxf(mx, acc[e]);
        float ex[8], ssum = 0.f;
#pragma unroll
        for (int e = 0; e < 8; e++) { ex[e] = __expf(acc[e] - mx); ssum += ex[e]; }
        const float inv = 1.f / ssum;
#pragma unroll
        for (int e = 0; e < 8; e++) scoresT[(size_t)e * TT + t] = ex[e] * inv;
    }
}

// ---------------- per-expert exact top-640 via bitonic sort (jax tie-break) ----------------
__global__ __launch_bounds__(1024) void k_topk(const float* __restrict__ scoresT,
                                               int* __restrict__ top_i, float* __restrict__ top_s) {
    __shared__ unsigned long long keys[4096];
    const int e = blockIdx.x;
    const int tid = threadIdx.x;
    for (int i = tid; i < 4096; i += 1024) {
        const float sv = scoresT[(size_t)e * TT + i];
        keys[i] = (((unsigned long long)__float_as_uint(sv)) << 32) |
                  (unsigned long long)(0xFFFFFFFFu - (unsigned)i);
    }
    __syncthreads();
    for (int k = 2; k <= 4096; k <<= 1) {
        for (int j = k >> 1; j > 0; j >>= 1) {
            for (int i = tid; i < 4096; i += 1024) {
                const int ixj = i ^ j;
                if (ixj > i) {
                    const bool up = ((i & k) == 0);
                    const unsigned long long a = keys[i], bb = keys[ixj];
                    if ((a > bb) == up) { keys[i] = bb; keys[ixj] = a; }
                }
            }
            __syncthreads();
        }
    }
    for (int c = tid; c < CAP; c += 1024) {
        const unsigned long long u = keys[4095 - c];
        top_i[e * CAP + c] = (int)(0xFFFFFFFFu - (unsigned)(u & 0xFFFFFFFFull));
        top_s[e * CAP + c] = __uint_as_float((unsigned)(u >> 32));
    }
}

// ---------------- explicit gather / scatter for MoE (fp32) ----------------
__global__ __launch_bounds__(192) void k_gather(const int* __restrict__ top_i, const float* __restrict__ hn,
                                                float* __restrict__ xg) {
    const int ec = blockIdx.x;
    const int tok = top_i[ec];
    const float4 v = *reinterpret_cast<const float4*>(hn + (size_t)tok * HH + threadIdx.x * 4);
    *reinterpret_cast<float4*>(xg + (size_t)ec * HH + threadIdx.x * 4) = v;
}

__global__ __launch_bounds__(192) void k_scatter(const int* __restrict__ top_i, const float* __restrict__ top_s,
                                                 const float* __restrict__ oute, float* __restrict__ h) {
    const int ec = blockIdx.x;
    const int tok = top_i[ec];
    const float sc = top_s[ec];
    const float4 v = *reinterpret_cast<const float4*>(oute + (size_t)ec * HH + threadIdx.x * 4);
    float* dst = h + (size_t)tok * HH + threadIdx.x * 4;
    atomicAdd(dst + 0, v.x * sc);
    atomicAdd(dst + 1, v.y * sc);
    atomicAdd(dst + 2, v.z * sc);
    atomicAdd(dst + 3, v.w * sc);
}

__global__ __launch_bounds__(512) void k_lb(const float* __restrict__ top_s, float* __restrict__ lb_out) {
    __shared__ float sums[8];
    const int w = threadIdx.x >> 6, lane = threadIdx.x & 63;
    float s = 0.f;
    for (int c = lane; c < CAP; c += 64) s += top_s[w * CAP + c];
#pragma unroll
    for (int off = 32; off; off >>= 1) s += __shfl_xor(s, off);
    if (lane == 0) sums[w] = s;
    __syncthreads();
    if (threadIdx.x == 0) {
        float mean = 0.f, load[8];
#pragma unroll
        for (int e2 = 0; e2 < 8; e2++) { load[e2] = sums[e2] * (1.f / 4096.f); mean += load[e2]; }
        mean *= 0.125f;
        float var = 0.f;
#pragma unroll
        for (int e2 = 0; e2 < 8; e2++) { const float d = load[e2] - mean; var += d * d; }
        lb_out[0] = var * (1.f / 7.f) * 8.f;
    }
}

__global__ void k_fin(const float* __restrict__ lb, float* __restrict__ dst) {
    if (threadIdx.x == 0 && blockIdx.x == 0) dst[0] = lb[0] + lb[1];
}

extern "C" void kernel_launch(void* const* d_in, const int* in_sizes, int n_in,
                              void* d_out, int out_size, void* d_ws, size_t ws_size,
                              hipStream_t stream)
{
    const int*   ids_raw = (const int*)d_in[0];
    const float* mask  = (const float*)d_in[1];
    const float* embw  = (const float*)d_in[2];
    const float* ln1g  = (const float*)d_in[3];
    const float* ln1b  = (const float*)d_in[4];
    const float* qw    = (const float*)d_in[5];
    const float* kw    = (const float*)d_in[6];
    const float* vw    = (const float*)d_in[7];
    const float* ow    = (const float*)d_in[8];
    const float* ln2g  = (const float*)d_in[9];
    const float* ln2b  = (const float*)d_in[10];
    const float* gw    = (const float*)d_in[11];
    const float* w1    = (const float*)d_in[12];
    const float* b1    = (const float*)d_in[13];
    const float* w2    = (const float*)d_in[14];
    const float* b2    = (const float*)d_in[15];
    const float* lnfg  = (const float*)d_in[16];
    const float* lnfb  = (const float*)d_in[17];
    const float* headw = (const float*)d_in[18];
    float* out = (float*)d_out;

    char* wsb = (char*)d_ws;
    size_t off = 0;
    auto alloc = [&](size_t bytes) -> void* {
        off = (off + 255) & ~(size_t)255;
        void* p = wsb + off;
        off += bytes;
        return p;
    };
    float* h0  = (float*)alloc((size_t)TT * HH * 4);
    float* h1b = (float*)alloc((size_t)TT * HH * 4);
    float* hn  = (float*)alloc((size_t)TT * HH * 4);
    float* q   = (float*)alloc((size_t)TT * HH * 4);
    float* kf  = (float*)alloc((size_t)TT * HDIM * 4);
    float* vf  = (float*)alloc((size_t)TT * HDIM * 4);
    float* scoresT = (float*)alloc((size_t)NEXP * TT * 4);
    int*   idsn    = (int*)alloc((size_t)TT * 4);
    int*   top_i   = (int*)alloc((size_t)NEXP * CAP * 4);
    float* top_s   = (float*)alloc((size_t)NEXP * CAP * 4);
    float* lb      = (float*)alloc(64);
    if (off > ws_size) return;

    char* outb = (char*)d_out;
    size_t ooff = 0;
    auto oalloc = [&](size_t bytes) -> void* {
        ooff = (ooff + 255) & ~(size_t)255;
        void* p = outb + ooff;
        ooff += bytes;
        return p;
    };
    float* xg   = (float*)oalloc((size_t)NEXP * CAP * HH * 4);
    float* act  = (float*)oalloc((size_t)NEXP * CAP * FDIM * 4);
    float* oute = (float*)oalloc((size_t)NEXP * CAP * HH * 4);

    k_ids<<<16, 256, 0, stream>>>(ids_raw, idsn);
    k_embed<<<TT, 192, 0, stream>>>(idsn, embw, h0);

    float* hc = h0;
    float* ho = h1b;
    for (int l = 0; l < 2; l++) {
        k_ln<<<TT, 64, 0, stream>>>(hc, ln1g + l * HH, ln1b + l * HH, hn);
        k_sgemm<true,false,false,false,false>
            <<<dim3(HH/64, TT/64, 1), 256, 0, stream>>>(
            hn, qw + (size_t)l * HH * HH, nullptr, nullptr, q, TT, HH, HH, 0, 0, 0, 0);
        k_sgemm<true,false,false,false,false>
            <<<dim3(1, TT/64, 1), 256, 0, stream>>>(
            hn, kw + (size_t)l * HDIM * HH, nullptr, nullptr, kf, TT, HDIM, HH, 0, 0, 0, 0);
        k_sgemm<true,false,false,false,false>
            <<<dim3(1, TT/64, 1), 256, 0, stream>>>(
            hn, vw + (size_t)l * HDIM * HH, nullptr, nullptr, vf, TT, HDIM, HH, 0, 0, 0, 0);
        k_attn2<<<2 * NHEAD * SEQ, 64, 0, stream>>>(q, kf, vf, mask, hn);
        k_sgemm<true,false,false,false,true>
            <<<dim3(HH/64, TT/64, 1), 256, 0, stream>>>(
            hn, ow + (size_t)l * HH * HH, nullptr, hc, ho, TT, HH, HH, 0, 0, 0, 0);
        k_ln<<<TT, 64, 0, stream>>>(ho, ln2g + l * HH, ln2b + l * HH, hn);
        k_gate<<<TT, 64, 0, stream>>>(hn, gw + (size_t)l * NEXP * HH, scoresT);
        k_topk<<<NEXP, 1024, 0, stream>>>(scoresT, top_i, top_s);
        k_gather<<<NEXP * CAP, 192, 0, stream>>>(top_i, hn, xg);
        k_sgemm<false,false,true,true,false>
            <<<dim3(FDIM/64, CAP/64, NEXP), 256, 0, stream>>>(
            xg, w1 + (size_t)l * NEXP * HH * FDIM, b1 + (size_t)l * NEXP * FDIM, nullptr, act,
            CAP, FDIM, HH, (long long)CAP * HH, (long long)HH * FDIM, FDIM, (long long)CAP * FDIM);
        k_sgemm<false,false,true,false,false>
            <<<dim3(HH/64, CAP/64, NEXP), 256, 0, stream>>>(
            act, w2 + (size_t)l * NEXP * FDIM * HH, b2 + (size_t)l * NEXP * HH, nullptr, oute,
            CAP, HH, FDIM, (long long)CAP * FDIM, (long long)FDIM * HH, HH, (long long)CAP * HH);
        k_scatter<<<NEXP * CAP, 192, 0, stream>>>(top_i, top_s, oute, ho);
        k_lb<<<1, 512, 0, stream>>>(top_s, lb + l);
        float* tmp = hc; hc = ho; ho = tmp;
    }
    k_ln<<<TT, 64, 0, stream>>>(hc, lnfg, lnfb, hn);
    // >>> single-variable test: MFMA core on the head GEMM only <<<
    k_gemm<true,true,false,false,false,float,float>
        <<<dim3(TT/64, VOCAB/64, 1), 256, 0, stream>>>(
        hn, headw, nullptr, nullptr, out, TT, VOCAB, HH, 0, 0, 0, 0);
    k_fin<<<1, 64, 0, stream>>>(lb, out + (size_t)TT * VOCAB);
}